// Round 12
// baseline (765.881 us; speedup 1.0000x reference)
//
#include <hip/hip_runtime.h>
#include <math.h>

#define NN 100000
#define NE 600000
#define NG 64
#define HD 128
#define NL 6
#define NB 1563   // gconv blocks = ceil(NN/64)
#define PSL 16    // pool slices per graph
#define ASTR 136  // LDS A-tile row stride in ushorts (272 B, 16-B aligned)

typedef unsigned short ushort_t;
typedef short short8 __attribute__((ext_vector_type(8)));
typedef float floatx4 __attribute__((ext_vector_type(4)));

__device__ __forceinline__ float bf2f(ushort_t u) {
    return __uint_as_float(((unsigned)u) << 16);
}
__device__ __forceinline__ ushort_t f2bf(float f) {
    unsigned u = __float_as_uint(f);
    unsigned r = (u + 0x7fffu + ((u >> 16) & 1u)) >> 16;   // round-to-nearest-even
    return (ushort_t)r;
}

// ---------------- x -> bf16 cast (once per call) ----------------

__global__ __launch_bounds__(256) void k_cast(const float* __restrict__ x,
                                              ushort_t* __restrict__ xb) {
    int i = blockIdx.x * 256 + threadIdx.x;
    if (i < NN * 32) {
        float4 v = ((const float4*)x)[i];
        ((ushort4*)xb)[i] = make_ushort4(f2bf(v.x), f2bf(v.y), f2bf(v.z), f2bf(v.w));
    }
}

// ---------------- W -> bf16 transpose: Wt[L][col][k] ----------------

__global__ __launch_bounds__(256) void k_wcast(const float* __restrict__ W,
                                               ushort_t* __restrict__ Wt) {
    const float* Wl = W + blockIdx.x * 16384;
    ushort_t* Wtl = Wt + blockIdx.x * 16384;
    for (int id = threadIdx.x; id < 16384; id += 256) {
        int k = id >> 7, c = id & 127;
        Wtl[c * 128 + k] = f2bf(Wl[id]);
    }
}

// ---------------- CSR build ----------------

__global__ __launch_bounds__(256) void k_hist(const int* __restrict__ ei, int* __restrict__ counts) {
    int e = blockIdx.x * 256 + threadIdx.x;
    if (e < NE) atomicAdd(&counts[ei[NE + e]], 1);
}

__global__ __launch_bounds__(256) void k_scan1(const int* __restrict__ counts, int* __restrict__ bsums) {
    __shared__ int s[256];
    int i = blockIdx.x * 256 + threadIdx.x;
    s[threadIdx.x] = (i < NN) ? counts[i] : 0;
    __syncthreads();
    for (int off = 128; off > 0; off >>= 1) {
        if (threadIdx.x < off) s[threadIdx.x] += s[threadIdx.x + off];
        __syncthreads();
    }
    if (threadIdx.x == 0) bsums[blockIdx.x] = s[0];
}

__global__ __launch_bounds__(512) void k_scan2(int* __restrict__ bsums, int nb) {
    __shared__ int s[512];
    int t = threadIdx.x;
    s[t] = (t < nb) ? bsums[t] : 0;
    __syncthreads();
    for (int off = 1; off < 512; off <<= 1) {
        int v = (t >= off) ? s[t - off] : 0;
        __syncthreads();
        s[t] += v;
        __syncthreads();
    }
    if (t < nb) bsums[t] = (t == 0) ? 0 : s[t - 1];
}

__global__ __launch_bounds__(256) void k_scan3(const int* __restrict__ counts, const int* __restrict__ bsums,
                                               int* __restrict__ rowptr) {
    __shared__ int s[256];
    int t = threadIdx.x;
    int i = blockIdx.x * 256 + t;
    int v = (i < NN) ? counts[i] : 0;
    s[t] = v;
    __syncthreads();
    for (int off = 1; off < 256; off <<= 1) {
        int u = (t >= off) ? s[t - off] : 0;
        __syncthreads();
        s[t] += u;
        __syncthreads();
    }
    if (i < NN) rowptr[i] = bsums[blockIdx.x] + s[t] - v;
    if (i == 0) rowptr[NN] = NE;
}

__global__ __launch_bounds__(256) void k_fill(const int* __restrict__ ei, const int* __restrict__ rowptr,
                                              int* __restrict__ cursor, int* __restrict__ colsrc) {
    int e = blockIdx.x * 256 + threadIdx.x;
    if (e < NE) {
        int d = ei[NE + e];
        int pos = rowptr[d] + atomicAdd(&cursor[d], 1);
        colsrc[pos] = ei[e];
    }
}

// ---------------- Degree sort (descending): counting sort into perm -------------

__global__ __launch_bounds__(256) void k_dhist(const int* __restrict__ rowptr,
                                               int* __restrict__ dcount) {
    __shared__ int lc[64];
    int t = threadIdx.x;
    if (t < 64) lc[t] = 0;
    __syncthreads();
    int n = blockIdx.x * 256 + t;
    if (n < NN) {
        int d = rowptr[n + 1] - rowptr[n];
        atomicAdd(&lc[min(d, 63)], 1);
    }
    __syncthreads();
    if (t < 64 && lc[t] > 0) atomicAdd(&dcount[t], lc[t]);
}

__global__ __launch_bounds__(64) void k_dscan(const int* __restrict__ dcount,
                                              int* __restrict__ doff) {
    int t = threadIdx.x;   // descending: bucket 63 first
    int s = 0;
    for (int b = t + 1; b < 64; ++b) s += dcount[b];
    doff[t] = s;
}

__global__ __launch_bounds__(256) void k_dfill(const int* __restrict__ rowptr,
                                               const int* __restrict__ doff,
                                               int* __restrict__ dcursor,
                                               int* __restrict__ perm) {
    __shared__ int lc[64], lbase[64];
    int t = threadIdx.x;
    if (t < 64) lc[t] = 0;
    __syncthreads();
    int n = blockIdx.x * 256 + t;
    int b = 0, my = 0;
    if (n < NN) {
        int d = rowptr[n + 1] - rowptr[n];
        b = min(d, 63);
        my = atomicAdd(&lc[b], 1);
    }
    __syncthreads();
    if (t < 64 && lc[t] > 0) lbase[t] = atomicAdd(&dcursor[t], lc[t]);
    __syncthreads();
    if (n < NN) perm[doff[b] + lbase[b] + my] = n;
}

// ---------------- Fused layer: coalesced gather -> LDS transpose -> MFMA ----------
// Per wave: 16 rows (degree-sorted via perm), gathered in groups of 4 with
// interleaved chains, lane = feature-pair -> each h-load instruction reads one
// FULL 256-B contiguous row (no 64-B sector waste; this is the layout that
// measured ~3.4 TB/s in R8 vs 1.83 TB/s for the fragment-direct gather).
// colsrc/rowptr indices are lane-invariant -> scalar loads. BN affine in fp32,
// pack bf16 into per-wave LDS tile, then ds_read_b128 A-fragments + MFMA
// (verified R9/R11 path; bitwise-identical accumulation order).

__global__ __launch_bounds__(256) void k_gconv(
    const ushort_t* __restrict__ hin, const int* __restrict__ perm,
    const int* __restrict__ rowptr, const int* __restrict__ colsrc,
    const float* __restrict__ stats, const float* __restrict__ bng,
    const float* __restrict__ bnb,
    const ushort_t* __restrict__ Wt, const float* __restrict__ bias,
    ushort_t* __restrict__ hout, float* __restrict__ partials) {
    __shared__ ushort_t Ab[64 * ASTR];   // 17408 B
    __shared__ float sstat[256];
    int t = threadIdx.x;
    sstat[t] = 0.f;
    int wave = t >> 6, lane = t & 63;
    int l15 = lane & 15, quad = lane >> 4;
    int rowbase = blockIdx.x * 64 + wave * 16;

    // deferred BN affine for this lane's two features (hoisted out of group loop)
    float sc0 = 1.f, sc1 = 1.f, sh0 = 0.f, sh1 = 0.f;
    {
        int c0 = lane * 2;
        if (stats != nullptr) {
            const float inv_n = 1.0f / (float)NN;
            float m0 = stats[c0] * inv_n, m1 = stats[c0 + 1] * inv_n;
            float var0 = fmaf(-m0, m0, stats[HD + c0] * inv_n);
            float var1 = fmaf(-m1, m1, stats[HD + c0 + 1] * inv_n);
            sc0 = bng[c0] * rsqrtf(var0 + 1e-5f);
            sc1 = bng[c0 + 1] * rsqrtf(var1 + 1e-5f);
            sh0 = bnb[c0] - m0 * sc0;
            sh1 = bnb[c0 + 1] - m1 * sc1;
        }
    }

    const ushort2* h2 = (const ushort2*)hin;
    #pragma unroll 1
    for (int g = 0; g < 4; ++g) {
        int b[4], d[4];
        #pragma unroll
        for (int i = 0; i < 4; ++i) {
            int idx = rowbase + g * 4 + i;
            bool v = idx < NN;
            int r = v ? perm[idx] : 0;
            b[i] = v ? rowptr[r] : 0;
            int e2 = v ? rowptr[r + 1] : 0;
            d[i] = e2 - b[i];
        }
        int maxd = max(max(d[0], d[1]), max(d[2], d[3]));
        float ax[4] = {0.f, 0.f, 0.f, 0.f};
        float ay[4] = {0.f, 0.f, 0.f, 0.f};
        int e = 0;
        for (; e + 1 < maxd; e += 2) {
            int sa[4], sb[4];
            float ma[4], mb[4];
            #pragma unroll
            for (int i = 0; i < 4; ++i) {
                bool oa = e < d[i], ob = e + 1 < d[i];
                sa[i] = colsrc[oa ? b[i] + e : 0];
                sb[i] = colsrc[ob ? b[i] + e + 1 : 0];
                ma[i] = oa ? 1.f : 0.f;
                mb[i] = ob ? 1.f : 0.f;
            }
            ushort2 va[4], vb[4];
            #pragma unroll
            for (int i = 0; i < 4; ++i) {
                va[i] = h2[(size_t)sa[i] * 64 + lane];
                vb[i] = h2[(size_t)sb[i] * 64 + lane];
            }
            #pragma unroll
            for (int i = 0; i < 4; ++i) {
                ax[i] = fmaf(ma[i], bf2f(va[i].x), ax[i]);
                ay[i] = fmaf(ma[i], bf2f(va[i].y), ay[i]);
                ax[i] = fmaf(mb[i], bf2f(vb[i].x), ax[i]);
                ay[i] = fmaf(mb[i], bf2f(vb[i].y), ay[i]);
            }
        }
        if (e < maxd) {
            #pragma unroll
            for (int i = 0; i < 4; ++i) {
                bool oa = e < d[i];
                int s0 = colsrc[oa ? b[i] + e : 0];
                float m0 = oa ? 1.f : 0.f;
                ushort2 v0 = h2[(size_t)s0 * 64 + lane];
                ax[i] = fmaf(m0, bf2f(v0.x), ax[i]);
                ay[i] = fmaf(m0, bf2f(v0.y), ay[i]);
            }
        }
        // BN affine + pack + LDS write (lane -> feature-pair column of row)
        #pragma unroll
        for (int i = 0; i < 4; ++i) {
            float degf = (float)d[i];
            float ox = fmaf(sc0, ax[i], degf * sh0);
            float oy = fmaf(sc1, ay[i], degf * sh1);
            int r = wave * 16 + g * 4 + i;
            *(ushort2*)&Ab[r * ASTR + 2 * lane] = make_ushort2(f2bf(ox), f2bf(oy));
        }
    }
    __syncthreads();   // LDS tile complete (also orders sstat zeroing)

    // A-fragments from LDS: A[m=l15][k=quad*8+j + s*32]
    short8 afrag[4];
    #pragma unroll
    for (int s = 0; s < 4; ++s)
        afrag[s] = *(const short8*)&Ab[(wave * 16 + l15) * ASTR + quad * 8 + s * 32];

    // MFMA phase (verified R9/R11 path)
    floatx4 acc[8];
    #pragma unroll
    for (int c = 0; c < 8; ++c) acc[c] = (floatx4){0.f, 0.f, 0.f, 0.f};
    #pragma unroll
    for (int c = 0; c < 8; ++c) {
        size_t boff = (size_t)(16 * c + l15) * 128 + quad * 8;
        #pragma unroll
        for (int s = 0; s < 4; ++s) {
            short8 bf = *(const short8*)(Wt + boff + 32 * s);
            acc[c] = __builtin_amdgcn_mfma_f32_16x16x32_bf16(afrag[s], bf, acc[c], 0, 0, 0);
        }
    }

    // output rows for this quad (original node ids)
    int prow[4];
    #pragma unroll
    for (int i = 0; i < 4; ++i) {
        int idx = rowbase + quad * 4 + i;
        prow[i] = (idx < NN) ? perm[idx] : 0;
    }

    int orow0 = rowbase + quad * 4;
    #pragma unroll
    for (int c = 0; c < 8; ++c) {
        int col = 16 * c + l15;
        float bv = bias[col];
        float ls = 0.f, lq = 0.f;
        #pragma unroll
        for (int i = 0; i < 4; ++i) {
            if (orow0 + i < NN) {
                float v = fmaxf(acc[c][i] + bv, 0.f);
                ushort_t bb = f2bf(v);
                hout[(size_t)prow[i] * 128 + col] = bb;
                float vr = bf2f(bb);
                ls += vr;
                lq = fmaf(vr, vr, lq);
            }
        }
        ls += __shfl_xor(ls, 16, 64);
        ls += __shfl_xor(ls, 32, 64);
        lq += __shfl_xor(lq, 16, 64);
        lq += __shfl_xor(lq, 32, 64);
        if (quad == 0) {
            atomicAdd(&sstat[col], ls);
            atomicAdd(&sstat[128 + col], lq);
        }
    }
    __syncthreads();
    partials[(size_t)blockIdx.x * 256 + t] = sstat[t];
}

// ---------------- Partial-stats reduction: 1563 x 256 -> 256 (64 blocks) -----------

__global__ __launch_bounds__(256) void k_red(const float* __restrict__ partials,
                                             float* __restrict__ stats) {
    int t = threadIdx.x;
    float s = 0.f;
    for (int r = blockIdx.x; r < NB; r += 64) s += partials[(size_t)r * 256 + t];
    atomicAdd(&stats[t], s);
}

// ---------------- Pooling, phase 1: per-(graph,slice) partial sums (bf16 h) ---------

__device__ __forceinline__ int lowerb(const int* __restrict__ b, int n, int key) {
    int lo = 0, hi = n;
    while (lo < hi) {
        int mid = (lo + hi) >> 1;
        if (b[mid] < key) lo = mid + 1;
        else hi = mid;
    }
    return lo;
}

__global__ __launch_bounds__(256) void k_pool1(
    const ushort_t* __restrict__ h, const int* __restrict__ batch,
    float* __restrict__ ppart) {
    int g = blockIdx.x >> 4;
    int sl = blockIdx.x & (PSL - 1);
    int lo = lowerb(batch, NN, g);
    int hi = lowerb(batch, NN, g + 1);
    int cnt = hi - lo;
    int a = lo + (int)(((long long)cnt * sl) >> 4);
    int b = lo + (int)(((long long)cnt * (sl + 1)) >> 4);
    int wave = threadIdx.x >> 6, lane = threadIdx.x & 63;
    const ushort2* h2 = (const ushort2*)h;
    float ax = 0.f, ay = 0.f;
    for (int n = a + wave; n < b; n += 4) {
        ushort2 v = h2[(size_t)n * 64 + lane];
        ax += bf2f(v.x);
        ay += bf2f(v.y);
    }
    __shared__ float2 red[4][64];
    red[wave][lane] = make_float2(ax, ay);
    __syncthreads();
    if (wave == 0) {
        float sx = 0.f, sy = 0.f;
        for (int w = 0; w < 4; ++w) {
            sx += red[w][lane].x;
            sy += red[w][lane].y;
        }
        ((float2*)ppart)[(size_t)blockIdx.x * 64 + lane] = make_float2(sx, sy);
    }
}

// ---------------- Pooling, phase 2: combine slices + deferred BN affine ----------------

__global__ __launch_bounds__(64) void k_pool2(
    const float* __restrict__ ppart, const int* __restrict__ batch,
    const float* __restrict__ stats, const float* __restrict__ bng, const float* __restrict__ bnb,
    float* __restrict__ pooled) {
    int g = blockIdx.x;
    int lane = threadIdx.x;
    float sx = 0.f, sy = 0.f;
    #pragma unroll
    for (int s = 0; s < PSL; ++s) {
        float2 v = ((const float2*)ppart)[(size_t)(g * PSL + s) * 64 + lane];
        sx += v.x;
        sy += v.y;
    }
    int cnt = lowerb(batch, NN, g + 1) - lowerb(batch, NN, g);
    int c0 = lane * 2;
    const float inv_n = 1.0f / (float)NN;
    float m0 = stats[c0] * inv_n, m1 = stats[c0 + 1] * inv_n;
    float var0 = fmaf(-m0, m0, stats[HD + c0] * inv_n);
    float var1 = fmaf(-m1, m1, stats[HD + c0 + 1] * inv_n);
    float sc0 = bng[c0] * rsqrtf(var0 + 1e-5f);
    float sc1 = bng[c0 + 1] * rsqrtf(var1 + 1e-5f);
    float sh0 = bnb[c0] - m0 * sc0;
    float sh1 = bnb[c0 + 1] - m1 * sc1;
    float denom = fmaxf((float)cnt, 1.f);
    float2 o;
    o.x = (sc0 * sx + (float)cnt * sh0) / denom;
    o.y = (sc1 * sy + (float)cnt * sh1) / denom;
    ((float2*)pooled)[g * 64 + lane] = o;
}

// ---------------- MLP head + log_softmax (one wave per graph) ----------------

__global__ __launch_bounds__(64) void k_head(
    const float* __restrict__ pooled, const float* __restrict__ w1, const float* __restrict__ b1,
    const float* __restrict__ w2, const float* __restrict__ b2, float* __restrict__ out) {
    int g = blockIdx.x;
    int j = threadIdx.x;
    float hid = b1[j];
    const float* p = pooled + g * 128;
    #pragma unroll 8
    for (int k = 0; k < 128; ++k) hid = fmaf(p[k], w1[k * 64 + j], hid);
    float o[4];
    #pragma unroll
    for (int c = 0; c < 4; ++c) {
        float v = hid * w2[j * 4 + c];
        #pragma unroll
        for (int off = 1; off < 64; off <<= 1) v += __shfl_xor(v, off, 64);
        o[c] = v + b2[c];
    }
    if (j == 0) {
        float mx = fmaxf(fmaxf(o[0], o[1]), fmaxf(o[2], o[3]));
        float se = expf(o[0] - mx) + expf(o[1] - mx) + expf(o[2] - mx) + expf(o[3] - mx);
        float ls = mx + logf(se);
        #pragma unroll
        for (int c = 0; c < 4; ++c) out[g * 4 + c] = o[c] - ls;
    }
}

extern "C" void kernel_launch(void* const* d_in, const int* in_sizes, int n_in,
                              void* d_out, int out_size, void* d_ws, size_t ws_size,
                              hipStream_t stream) {
    const float* x = (const float*)d_in[0];
    const int* ei = (const int*)d_in[1];
    const int* batch = (const int*)d_in[2];
    const float* conv_w = (const float*)d_in[3];
    const float* conv_b = (const float*)d_in[4];
    const float* bn_g = (const float*)d_in[5];
    const float* bn_b = (const float*)d_in[6];
    const float* l1w = (const float*)d_in[7];
    const float* l1b = (const float*)d_in[8];
    const float* l2w = (const float*)d_in[9];
    const float* l2b = (const float*)d_in[10];
    float* out = (float*)d_out;
    (void)in_sizes; (void)n_in; (void)out_size; (void)ws_size;

    char* ws = (char*)d_ws;
    int* counts = (int*)(ws + 0);               // 400000 B
    int* dcount = (int*)(ws + 0);               // 256 B   (after k_fill)
    int* dcursor = (int*)(ws + 256);            // 256 B
    int* doff = (int*)(ws + 512);               // 256 B
    int* cursor = (int*)(ws + 400000);          // 400000 B
    int* perm = (int*)(ws + 400000);            // reuse   (after k_fill)
    float* stats = (float*)(ws + 800000);       // 6*256 floats = 6144 B
    const size_t zero_bytes = 806144;           // counts + cursor + stats
    int* rowptr = (int*)(ws + 806144);          // 100001 ints
    int* bsums = (int*)(ws + 1206400);          // 391 ints
    int* colsrc = (int*)(ws + 1208192);         // 600000 ints -> ends 3608192
    float* pooled = (float*)(ws + 3608192);     // 64*128 floats -> ends 3640960
    float* ppart = (float*)(ws + 3641344);      // 1024*128 floats -> ends 4165632
    float* partials = (float*)(ws + 4165632);   // 1563*256 floats -> ends 5766144
    ushort_t* xb = (ushort_t*)(ws + 5766656);   // 25600000 B -> ends 31366656
    ushort_t* hb0 = (ushort_t*)(ws + 31366656); // 25600000 B -> ends 56966656
    ushort_t* hb1 = (ushort_t*)(ws + 56966656); // 25600000 B -> ends 82566656
    ushort_t* wtbuf = (ushort_t*)(ws + 82566656); // 196608 B -> ends 82763264

    hipMemsetAsync(ws, 0, zero_bytes, stream);

    k_cast<<<(NN * 32 + 255) / 256, 256, 0, stream>>>(x, xb);
    k_wcast<<<NL, 256, 0, stream>>>(conv_w, wtbuf);

    int ebl = (NE + 255) / 256;
    int nb1 = (NN + 255) / 256;  // 391
    k_hist<<<ebl, 256, 0, stream>>>(ei, counts);
    k_scan1<<<nb1, 256, 0, stream>>>(counts, bsums);
    k_scan2<<<1, 512, 0, stream>>>(bsums, nb1);
    k_scan3<<<nb1, 256, 0, stream>>>(counts, bsums, rowptr);
    k_fill<<<ebl, 256, 0, stream>>>(ei, rowptr, cursor, colsrc);

    // degree counting sort (descending) into perm
    hipMemsetAsync(ws, 0, 512, stream);   // dcount + dcursor
    k_dhist<<<nb1, 256, 0, stream>>>(rowptr, dcount);
    k_dscan<<<1, 64, 0, stream>>>(dcount, doff);
    k_dfill<<<nb1, 256, 0, stream>>>(rowptr, doff, dcursor, perm);

    // ping-pong h buffers: gconv reads hin, writes hout (never in place)
    ushort_t* hb[2] = {hb0, hb1};
    for (int L = 0; L < NL; ++L) {
        const ushort_t* hin = (L == 0) ? xb : hb[(L + 1) & 1];
        ushort_t* hout = hb[L & 1];
        const float* lstats = (L == 0) ? nullptr : (stats + (L - 1) * 256);
        const float* lg = (L == 0) ? nullptr : (bn_g + (L - 1) * 128);
        const float* lb = (L == 0) ? nullptr : (bn_b + (L - 1) * 128);
        k_gconv<<<NB, 256, 0, stream>>>(hin, perm, rowptr, colsrc, lstats, lg, lb,
                                        wtbuf + L * 16384, conv_b + L * 128,
                                        hout, partials);
        k_red<<<64, 256, 0, stream>>>(partials, stats + L * 256);
    }
    // final h is hb[5&1] = hb1
    k_pool1<<<NG * PSL, 256, 0, stream>>>(hb1, batch, ppart);
    k_pool2<<<NG, 64, 0, stream>>>(ppart, batch, stats + 5 * 256, bn_g + 5 * 128, bn_b + 5 * 128, pooled);
    k_head<<<NG, 64, 0, stream>>>(pooled, l1w, l1b, l2w, l2b, out);
}

// Round 13
// 754.592 us; speedup vs baseline: 1.0150x; 1.0150x over previous
//
#include <hip/hip_runtime.h>
#include <math.h>

#define NN 100000
#define NE 600000
#define NG 64
#define HD 128
#define NL 6
#define NB 1563   // gconv blocks = ceil(NN/64)
#define PSL 16    // pool slices per graph
#define ASTR 136  // LDS A-tile row stride in ushorts (272 B, 16-B aligned)

typedef unsigned short ushort_t;
typedef short short8 __attribute__((ext_vector_type(8)));
typedef float floatx4 __attribute__((ext_vector_type(4)));

__device__ __forceinline__ float bf2f(ushort_t u) {
    return __uint_as_float(((unsigned)u) << 16);
}
__device__ __forceinline__ ushort_t f2bf(float f) {
    unsigned u = __float_as_uint(f);
    unsigned r = (u + 0x7fffu + ((u >> 16) & 1u)) >> 16;   // round-to-nearest-even
    return (ushort_t)r;
}

// ---------------- x -> bf16 cast (once per call) ----------------

__global__ __launch_bounds__(256) void k_cast(const float* __restrict__ x,
                                              ushort_t* __restrict__ xb) {
    int i = blockIdx.x * 256 + threadIdx.x;
    if (i < NN * 32) {
        float4 v = ((const float4*)x)[i];
        ((ushort4*)xb)[i] = make_ushort4(f2bf(v.x), f2bf(v.y), f2bf(v.z), f2bf(v.w));
    }
}

// ---------------- W -> bf16 transpose: Wt[L][col][k] ----------------

__global__ __launch_bounds__(256) void k_wcast(const float* __restrict__ W,
                                               ushort_t* __restrict__ Wt) {
    const float* Wl = W + blockIdx.x * 16384;
    ushort_t* Wtl = Wt + blockIdx.x * 16384;
    for (int id = threadIdx.x; id < 16384; id += 256) {
        int k = id >> 7, c = id & 127;
        Wtl[c * 128 + k] = f2bf(Wl[id]);
    }
}

// ---------------- CSR build ----------------

__global__ __launch_bounds__(256) void k_hist(const int* __restrict__ ei, int* __restrict__ counts) {
    int e = blockIdx.x * 256 + threadIdx.x;
    if (e < NE) atomicAdd(&counts[ei[NE + e]], 1);
}

__global__ __launch_bounds__(256) void k_scan1(const int* __restrict__ counts, int* __restrict__ bsums) {
    __shared__ int s[256];
    int i = blockIdx.x * 256 + threadIdx.x;
    s[threadIdx.x] = (i < NN) ? counts[i] : 0;
    __syncthreads();
    for (int off = 128; off > 0; off >>= 1) {
        if (threadIdx.x < off) s[threadIdx.x] += s[threadIdx.x + off];
        __syncthreads();
    }
    if (threadIdx.x == 0) bsums[blockIdx.x] = s[0];
}

__global__ __launch_bounds__(512) void k_scan2(int* __restrict__ bsums, int nb) {
    __shared__ int s[512];
    int t = threadIdx.x;
    s[t] = (t < nb) ? bsums[t] : 0;
    __syncthreads();
    for (int off = 1; off < 512; off <<= 1) {
        int v = (t >= off) ? s[t - off] : 0;
        __syncthreads();
        s[t] += v;
        __syncthreads();
    }
    if (t < nb) bsums[t] = (t == 0) ? 0 : s[t - 1];
}

__global__ __launch_bounds__(256) void k_scan3(const int* __restrict__ counts, const int* __restrict__ bsums,
                                               int* __restrict__ rowptr) {
    __shared__ int s[256];
    int t = threadIdx.x;
    int i = blockIdx.x * 256 + t;
    int v = (i < NN) ? counts[i] : 0;
    s[t] = v;
    __syncthreads();
    for (int off = 1; off < 256; off <<= 1) {
        int u = (t >= off) ? s[t - off] : 0;
        __syncthreads();
        s[t] += u;
        __syncthreads();
    }
    if (i < NN) rowptr[i] = bsums[blockIdx.x] + s[t] - v;
    if (i == 0) rowptr[NN] = NE;
}

__global__ __launch_bounds__(256) void k_fill(const int* __restrict__ ei, const int* __restrict__ rowptr,
                                              int* __restrict__ cursor, int* __restrict__ colsrc) {
    int e = blockIdx.x * 256 + threadIdx.x;
    if (e < NE) {
        int d = ei[NE + e];
        int pos = rowptr[d] + atomicAdd(&cursor[d], 1);
        colsrc[pos] = ei[e];
    }
}

// ---------------- Degree sort (descending): counting sort into perm -------------

__global__ __launch_bounds__(256) void k_dhist(const int* __restrict__ rowptr,
                                               int* __restrict__ dcount) {
    __shared__ int lc[64];
    int t = threadIdx.x;
    if (t < 64) lc[t] = 0;
    __syncthreads();
    int n = blockIdx.x * 256 + t;
    if (n < NN) {
        int d = rowptr[n + 1] - rowptr[n];
        atomicAdd(&lc[min(d, 63)], 1);
    }
    __syncthreads();
    if (t < 64 && lc[t] > 0) atomicAdd(&dcount[t], lc[t]);
}

__global__ __launch_bounds__(64) void k_dscan(const int* __restrict__ dcount,
                                              int* __restrict__ doff) {
    int t = threadIdx.x;   // descending: bucket 63 first
    int s = 0;
    for (int b = t + 1; b < 64; ++b) s += dcount[b];
    doff[t] = s;
}

__global__ __launch_bounds__(256) void k_dfill(const int* __restrict__ rowptr,
                                               const int* __restrict__ doff,
                                               int* __restrict__ dcursor,
                                               int* __restrict__ perm) {
    __shared__ int lc[64], lbase[64];
    int t = threadIdx.x;
    if (t < 64) lc[t] = 0;
    __syncthreads();
    int n = blockIdx.x * 256 + t;
    int b = 0, my = 0;
    if (n < NN) {
        int d = rowptr[n + 1] - rowptr[n];
        b = min(d, 63);
        my = atomicAdd(&lc[b], 1);
    }
    __syncthreads();
    if (t < 64 && lc[t] > 0) lbase[t] = atomicAdd(&dcursor[t], lc[t]);
    __syncthreads();
    if (n < NN) perm[doff[b] + lbase[b] + my] = n;
}

// ---------------- Fused layer: deep-pipelined gather -> LDS -> MFMA ----------
// Per wave: 16 rows (degree-sorted), gathered in groups of 4; 4-edge unroll ->
// 16 independent 256-B h-load instructions in flight per step; next step's 16
// colsrc indices prefetched BEFORE consuming current h (index latency overlaps
// data latency). __launch_bounds__(256,4) raises VGPR cap to 128 so the
// compiler keeps the loads in flight (work is only ~6 waves/SIMD, occupancy
// is not binding). Accumulation order per row unchanged -> bitwise-identical.

__global__ __launch_bounds__(256, 4) void k_gconv(
    const ushort_t* __restrict__ hin, const int* __restrict__ perm,
    const int* __restrict__ rowptr, const int* __restrict__ colsrc,
    const float* __restrict__ stats, const float* __restrict__ bng,
    const float* __restrict__ bnb,
    const ushort_t* __restrict__ Wt, const float* __restrict__ bias,
    ushort_t* __restrict__ hout, float* __restrict__ partials) {
    __shared__ ushort_t Ab[64 * ASTR];   // 17408 B
    __shared__ float sstat[256];
    int t = threadIdx.x;
    sstat[t] = 0.f;
    int wave = t >> 6, lane = t & 63;
    int l15 = lane & 15, quad = lane >> 4;
    int rowbase = blockIdx.x * 64 + wave * 16;

    // deferred BN affine for this lane's two features
    float sc0 = 1.f, sc1 = 1.f, sh0 = 0.f, sh1 = 0.f;
    {
        int c0 = lane * 2;
        if (stats != nullptr) {
            const float inv_n = 1.0f / (float)NN;
            float m0 = stats[c0] * inv_n, m1 = stats[c0 + 1] * inv_n;
            float var0 = fmaf(-m0, m0, stats[HD + c0] * inv_n);
            float var1 = fmaf(-m1, m1, stats[HD + c0 + 1] * inv_n);
            sc0 = bng[c0] * rsqrtf(var0 + 1e-5f);
            sc1 = bng[c0 + 1] * rsqrtf(var1 + 1e-5f);
            sh0 = bnb[c0] - m0 * sc0;
            sh1 = bnb[c0 + 1] - m1 * sc1;
        }
    }

    const ushort2* h2 = (const ushort2*)hin;
    #pragma unroll 1
    for (int g = 0; g < 4; ++g) {
        int b[4], d[4];
        #pragma unroll
        for (int i = 0; i < 4; ++i) {
            int idx = rowbase + g * 4 + i;
            bool v = idx < NN;
            int r = v ? perm[idx] : 0;
            b[i] = v ? rowptr[r] : 0;
            int e2 = v ? rowptr[r + 1] : 0;
            d[i] = e2 - b[i];
        }
        int maxd = max(max(d[0], d[1]), max(d[2], d[3]));
        float ax[4] = {0.f, 0.f, 0.f, 0.f};
        float ay[4] = {0.f, 0.f, 0.f, 0.f};

        // prefetch first 4 edges x 4 rows of indices
        int cs[16];
        #pragma unroll
        for (int eo = 0; eo < 4; ++eo)
            #pragma unroll
            for (int i = 0; i < 4; ++i)
                cs[eo * 4 + i] = colsrc[(eo < d[i]) ? b[i] + eo : 0];

        #pragma unroll 1
        for (int e = 0; e < maxd; e += 4) {
            // issue 16 h loads (independent)
            ushort2 hv[16];
            #pragma unroll
            for (int u2 = 0; u2 < 16; ++u2)
                hv[u2] = h2[(size_t)cs[u2] * 64 + lane];
            // prefetch next 16 indices (independent of hv)
            int ncs[16];
            #pragma unroll
            for (int eo = 0; eo < 4; ++eo)
                #pragma unroll
                for (int i = 0; i < 4; ++i) {
                    int ee = e + 4 + eo;
                    ncs[eo * 4 + i] = colsrc[(ee < d[i]) ? b[i] + ee : 0];
                }
            // consume in ascending edge order (bitwise == previous rounds)
            #pragma unroll
            for (int eo = 0; eo < 4; ++eo)
                #pragma unroll
                for (int i = 0; i < 4; ++i) {
                    float m = (e + eo < d[i]) ? 1.f : 0.f;
                    ushort2 v = hv[eo * 4 + i];
                    ax[i] = fmaf(m, bf2f(v.x), ax[i]);
                    ay[i] = fmaf(m, bf2f(v.y), ay[i]);
                }
            #pragma unroll
            for (int u2 = 0; u2 < 16; ++u2) cs[u2] = ncs[u2];
        }

        // BN affine + pack + LDS write (lane -> feature-pair column of row)
        #pragma unroll
        for (int i = 0; i < 4; ++i) {
            float degf = (float)d[i];
            float ox = fmaf(sc0, ax[i], degf * sh0);
            float oy = fmaf(sc1, ay[i], degf * sh1);
            int r = wave * 16 + g * 4 + i;
            *(ushort2*)&Ab[r * ASTR + 2 * lane] = make_ushort2(f2bf(ox), f2bf(oy));
        }
    }
    __syncthreads();   // LDS tile complete (also orders sstat zeroing)

    // A-fragments from LDS: A[m=l15][k=quad*8+j + s*32]
    short8 afrag[4];
    #pragma unroll
    for (int s = 0; s < 4; ++s)
        afrag[s] = *(const short8*)&Ab[(wave * 16 + l15) * ASTR + quad * 8 + s * 32];

    // MFMA phase (verified R9/R11 path)
    floatx4 acc[8];
    #pragma unroll
    for (int c = 0; c < 8; ++c) acc[c] = (floatx4){0.f, 0.f, 0.f, 0.f};
    #pragma unroll
    for (int c = 0; c < 8; ++c) {
        size_t boff = (size_t)(16 * c + l15) * 128 + quad * 8;
        #pragma unroll
        for (int s = 0; s < 4; ++s) {
            short8 bf = *(const short8*)(Wt + boff + 32 * s);
            acc[c] = __builtin_amdgcn_mfma_f32_16x16x32_bf16(afrag[s], bf, acc[c], 0, 0, 0);
        }
    }

    // output rows for this quad (original node ids)
    int prow[4];
    #pragma unroll
    for (int i = 0; i < 4; ++i) {
        int idx = rowbase + quad * 4 + i;
        prow[i] = (idx < NN) ? perm[idx] : 0;
    }

    int orow0 = rowbase + quad * 4;
    #pragma unroll
    for (int c = 0; c < 8; ++c) {
        int col = 16 * c + l15;
        float bv = bias[col];
        float ls = 0.f, lq = 0.f;
        #pragma unroll
        for (int i = 0; i < 4; ++i) {
            if (orow0 + i < NN) {
                float v = fmaxf(acc[c][i] + bv, 0.f);
                ushort_t bb = f2bf(v);
                hout[(size_t)prow[i] * 128 + col] = bb;
                float vr = bf2f(bb);
                ls += vr;
                lq = fmaf(vr, vr, lq);
            }
        }
        ls += __shfl_xor(ls, 16, 64);
        ls += __shfl_xor(ls, 32, 64);
        lq += __shfl_xor(lq, 16, 64);
        lq += __shfl_xor(lq, 32, 64);
        if (quad == 0) {
            atomicAdd(&sstat[col], ls);
            atomicAdd(&sstat[128 + col], lq);
        }
    }
    __syncthreads();
    partials[(size_t)blockIdx.x * 256 + t] = sstat[t];
}

// ---------------- Partial-stats reduction: 1563 x 256 -> 256 (64 blocks) -----------

__global__ __launch_bounds__(256) void k_red(const float* __restrict__ partials,
                                             float* __restrict__ stats) {
    int t = threadIdx.x;
    float s = 0.f;
    for (int r = blockIdx.x; r < NB; r += 64) s += partials[(size_t)r * 256 + t];
    atomicAdd(&stats[t], s);
}

// ---------------- Pooling, phase 1: per-(graph,slice) partial sums (bf16 h) ---------

__device__ __forceinline__ int lowerb(const int* __restrict__ b, int n, int key) {
    int lo = 0, hi = n;
    while (lo < hi) {
        int mid = (lo + hi) >> 1;
        if (b[mid] < key) lo = mid + 1;
        else hi = mid;
    }
    return lo;
}

__global__ __launch_bounds__(256) void k_pool1(
    const ushort_t* __restrict__ h, const int* __restrict__ batch,
    float* __restrict__ ppart) {
    int g = blockIdx.x >> 4;
    int sl = blockIdx.x & (PSL - 1);
    int lo = lowerb(batch, NN, g);
    int hi = lowerb(batch, NN, g + 1);
    int cnt = hi - lo;
    int a = lo + (int)(((long long)cnt * sl) >> 4);
    int b = lo + (int)(((long long)cnt * (sl + 1)) >> 4);
    int wave = threadIdx.x >> 6, lane = threadIdx.x & 63;
    const ushort2* h2 = (const ushort2*)h;
    float ax = 0.f, ay = 0.f;
    for (int n = a + wave; n < b; n += 4) {
        ushort2 v = h2[(size_t)n * 64 + lane];
        ax += bf2f(v.x);
        ay += bf2f(v.y);
    }
    __shared__ float2 red[4][64];
    red[wave][lane] = make_float2(ax, ay);
    __syncthreads();
    if (wave == 0) {
        float sx = 0.f, sy = 0.f;
        for (int w = 0; w < 4; ++w) {
            sx += red[w][lane].x;
            sy += red[w][lane].y;
        }
        ((float2*)ppart)[(size_t)blockIdx.x * 64 + lane] = make_float2(sx, sy);
    }
}

// ---------------- Pooling, phase 2: combine slices + deferred BN affine ----------------

__global__ __launch_bounds__(64) void k_pool2(
    const float* __restrict__ ppart, const int* __restrict__ batch,
    const float* __restrict__ stats, const float* __restrict__ bng, const float* __restrict__ bnb,
    float* __restrict__ pooled) {
    int g = blockIdx.x;
    int lane = threadIdx.x;
    float sx = 0.f, sy = 0.f;
    #pragma unroll
    for (int s = 0; s < PSL; ++s) {
        float2 v = ((const float2*)ppart)[(size_t)(g * PSL + s) * 64 + lane];
        sx += v.x;
        sy += v.y;
    }
    int cnt = lowerb(batch, NN, g + 1) - lowerb(batch, NN, g);
    int c0 = lane * 2;
    const float inv_n = 1.0f / (float)NN;
    float m0 = stats[c0] * inv_n, m1 = stats[c0 + 1] * inv_n;
    float var0 = fmaf(-m0, m0, stats[HD + c0] * inv_n);
    float var1 = fmaf(-m1, m1, stats[HD + c0 + 1] * inv_n);
    float sc0 = bng[c0] * rsqrtf(var0 + 1e-5f);
    float sc1 = bng[c0 + 1] * rsqrtf(var1 + 1e-5f);
    float sh0 = bnb[c0] - m0 * sc0;
    float sh1 = bnb[c0 + 1] - m1 * sc1;
    float denom = fmaxf((float)cnt, 1.f);
    float2 o;
    o.x = (sc0 * sx + (float)cnt * sh0) / denom;
    o.y = (sc1 * sy + (float)cnt * sh1) / denom;
    ((float2*)pooled)[g * 64 + lane] = o;
}

// ---------------- MLP head + log_softmax (one wave per graph) ----------------

__global__ __launch_bounds__(64) void k_head(
    const float* __restrict__ pooled, const float* __restrict__ w1, const float* __restrict__ b1,
    const float* __restrict__ w2, const float* __restrict__ b2, float* __restrict__ out) {
    int g = blockIdx.x;
    int j = threadIdx.x;
    float hid = b1[j];
    const float* p = pooled + g * 128;
    #pragma unroll 8
    for (int k = 0; k < 128; ++k) hid = fmaf(p[k], w1[k * 64 + j], hid);
    float o[4];
    #pragma unroll
    for (int c = 0; c < 4; ++c) {
        float v = hid * w2[j * 4 + c];
        #pragma unroll
        for (int off = 1; off < 64; off <<= 1) v += __shfl_xor(v, off, 64);
        o[c] = v + b2[c];
    }
    if (j == 0) {
        float mx = fmaxf(fmaxf(o[0], o[1]), fmaxf(o[2], o[3]));
        float se = expf(o[0] - mx) + expf(o[1] - mx) + expf(o[2] - mx) + expf(o[3] - mx);
        float ls = mx + logf(se);
        #pragma unroll
        for (int c = 0; c < 4; ++c) out[g * 4 + c] = o[c] - ls;
    }
}

extern "C" void kernel_launch(void* const* d_in, const int* in_sizes, int n_in,
                              void* d_out, int out_size, void* d_ws, size_t ws_size,
                              hipStream_t stream) {
    const float* x = (const float*)d_in[0];
    const int* ei = (const int*)d_in[1];
    const int* batch = (const int*)d_in[2];
    const float* conv_w = (const float*)d_in[3];
    const float* conv_b = (const float*)d_in[4];
    const float* bn_g = (const float*)d_in[5];
    const float* bn_b = (const float*)d_in[6];
    const float* l1w = (const float*)d_in[7];
    const float* l1b = (const float*)d_in[8];
    const float* l2w = (const float*)d_in[9];
    const float* l2b = (const float*)d_in[10];
    float* out = (float*)d_out;
    (void)in_sizes; (void)n_in; (void)out_size; (void)ws_size;

    char* ws = (char*)d_ws;
    int* counts = (int*)(ws + 0);               // 400000 B
    int* dcount = (int*)(ws + 0);               // 256 B   (after k_fill)
    int* dcursor = (int*)(ws + 256);            // 256 B
    int* doff = (int*)(ws + 512);               // 256 B
    int* cursor = (int*)(ws + 400000);          // 400000 B
    int* perm = (int*)(ws + 400000);            // reuse   (after k_fill)
    float* stats = (float*)(ws + 800000);       // 6*256 floats = 6144 B
    const size_t zero_bytes = 806144;           // counts + cursor + stats
    int* rowptr = (int*)(ws + 806144);          // 100001 ints
    int* bsums = (int*)(ws + 1206400);          // 391 ints
    int* colsrc = (int*)(ws + 1208192);         // 600000 ints -> ends 3608192
    float* pooled = (float*)(ws + 3608192);     // 64*128 floats -> ends 3640960
    float* ppart = (float*)(ws + 3641344);      // 1024*128 floats -> ends 4165632
    float* partials = (float*)(ws + 4165632);   // 1563*256 floats -> ends 5766144
    ushort_t* xb = (ushort_t*)(ws + 5766656);   // 25600000 B -> ends 31366656
    ushort_t* hb0 = (ushort_t*)(ws + 31366656); // 25600000 B -> ends 56966656
    ushort_t* hb1 = (ushort_t*)(ws + 56966656); // 25600000 B -> ends 82566656
    ushort_t* wtbuf = (ushort_t*)(ws + 82566656); // 196608 B -> ends 82763264

    hipMemsetAsync(ws, 0, zero_bytes, stream);

    k_cast<<<(NN * 32 + 255) / 256, 256, 0, stream>>>(x, xb);
    k_wcast<<<NL, 256, 0, stream>>>(conv_w, wtbuf);

    int ebl = (NE + 255) / 256;
    int nb1 = (NN + 255) / 256;  // 391
    k_hist<<<ebl, 256, 0, stream>>>(ei, counts);
    k_scan1<<<nb1, 256, 0, stream>>>(counts, bsums);
    k_scan2<<<1, 512, 0, stream>>>(bsums, nb1);
    k_scan3<<<nb1, 256, 0, stream>>>(counts, bsums, rowptr);
    k_fill<<<ebl, 256, 0, stream>>>(ei, rowptr, cursor, colsrc);

    // degree counting sort (descending) into perm
    hipMemsetAsync(ws, 0, 512, stream);   // dcount + dcursor
    k_dhist<<<nb1, 256, 0, stream>>>(rowptr, dcount);
    k_dscan<<<1, 64, 0, stream>>>(dcount, doff);
    k_dfill<<<nb1, 256, 0, stream>>>(rowptr, doff, dcursor, perm);

    // ping-pong h buffers: gconv reads hin, writes hout (never in place)
    ushort_t* hb[2] = {hb0, hb1};
    for (int L = 0; L < NL; ++L) {
        const ushort_t* hin = (L == 0) ? xb : hb[(L + 1) & 1];
        ushort_t* hout = hb[L & 1];
        const float* lstats = (L == 0) ? nullptr : (stats + (L - 1) * 256);
        const float* lg = (L == 0) ? nullptr : (bn_g + (L - 1) * 128);
        const float* lb = (L == 0) ? nullptr : (bn_b + (L - 1) * 128);
        k_gconv<<<NB, 256, 0, stream>>>(hin, perm, rowptr, colsrc, lstats, lg, lb,
                                        wtbuf + L * 16384, conv_b + L * 128,
                                        hout, partials);
        k_red<<<64, 256, 0, stream>>>(partials, stats + L * 256);
    }
    // final h is hb[5&1] = hb1
    k_pool1<<<NG * PSL, 256, 0, stream>>>(hb1, batch, ppart);
    k_pool2<<<NG, 64, 0, stream>>>(ppart, batch, stats + 5 * 256, bn_g + 5 * 128, bn_b + 5 * 128, pooled);
    k_head<<<NG, 64, 0, stream>>>(pooled, l1w, l1b, l2w, l2b, out);
}

// Round 14
// 695.056 us; speedup vs baseline: 1.1019x; 1.0857x over previous
//
#include <hip/hip_runtime.h>
#include <math.h>

#define NN 100000
#define NE 600000
#define NG 64
#define HD 128
#define NL 6
#define NB 1563   // gconv blocks = ceil(NN/64)
#define PSL 16    // pool slices per graph
#define ASTR 136  // LDS A-tile row stride in ushorts (272 B, 16-B aligned)

typedef unsigned short ushort_t;
typedef short short8 __attribute__((ext_vector_type(8)));
typedef float floatx4 __attribute__((ext_vector_type(4)));

__device__ __forceinline__ float bf2f(ushort_t u) {
    return __uint_as_float(((unsigned)u) << 16);
}
__device__ __forceinline__ ushort_t f2bf(float f) {
    unsigned u = __float_as_uint(f);
    unsigned r = (u + 0x7fffu + ((u >> 16) & 1u)) >> 16;   // round-to-nearest-even
    return (ushort_t)r;
}

// ---------------- x -> bf16 cast (once per call) ----------------

__global__ __launch_bounds__(256) void k_cast(const float* __restrict__ x,
                                              ushort_t* __restrict__ xb) {
    int i = blockIdx.x * 256 + threadIdx.x;
    if (i < NN * 32) {
        float4 v = ((const float4*)x)[i];
        ((ushort4*)xb)[i] = make_ushort4(f2bf(v.x), f2bf(v.y), f2bf(v.z), f2bf(v.w));
    }
}

// ---------------- W -> bf16 transpose: Wt[L][col][k] ----------------

__global__ __launch_bounds__(256) void k_wcast(const float* __restrict__ W,
                                               ushort_t* __restrict__ Wt) {
    const float* Wl = W + blockIdx.x * 16384;
    ushort_t* Wtl = Wt + blockIdx.x * 16384;
    for (int id = threadIdx.x; id < 16384; id += 256) {
        int k = id >> 7, c = id & 127;
        Wtl[c * 128 + k] = f2bf(Wl[id]);
    }
}

// ---------------- CSR build ----------------

__global__ __launch_bounds__(256) void k_hist(const int* __restrict__ ei, int* __restrict__ counts) {
    int e = blockIdx.x * 256 + threadIdx.x;
    if (e < NE) atomicAdd(&counts[ei[NE + e]], 1);
}

__global__ __launch_bounds__(256) void k_scan1(const int* __restrict__ counts, int* __restrict__ bsums) {
    __shared__ int s[256];
    int i = blockIdx.x * 256 + threadIdx.x;
    s[threadIdx.x] = (i < NN) ? counts[i] : 0;
    __syncthreads();
    for (int off = 128; off > 0; off >>= 1) {
        if (threadIdx.x < off) s[threadIdx.x] += s[threadIdx.x + off];
        __syncthreads();
    }
    if (threadIdx.x == 0) bsums[blockIdx.x] = s[0];
}

__global__ __launch_bounds__(512) void k_scan2(int* __restrict__ bsums, int nb) {
    __shared__ int s[512];
    int t = threadIdx.x;
    s[t] = (t < nb) ? bsums[t] : 0;
    __syncthreads();
    for (int off = 1; off < 512; off <<= 1) {
        int v = (t >= off) ? s[t - off] : 0;
        __syncthreads();
        s[t] += v;
        __syncthreads();
    }
    if (t < nb) bsums[t] = (t == 0) ? 0 : s[t - 1];
}

__global__ __launch_bounds__(256) void k_scan3(const int* __restrict__ counts, const int* __restrict__ bsums,
                                               int* __restrict__ rowptr) {
    __shared__ int s[256];
    int t = threadIdx.x;
    int i = blockIdx.x * 256 + t;
    int v = (i < NN) ? counts[i] : 0;
    s[t] = v;
    __syncthreads();
    for (int off = 1; off < 256; off <<= 1) {
        int u = (t >= off) ? s[t - off] : 0;
        __syncthreads();
        s[t] += u;
        __syncthreads();
    }
    if (i < NN) rowptr[i] = bsums[blockIdx.x] + s[t] - v;
    if (i == 0) rowptr[NN] = NE;
}

__global__ __launch_bounds__(256) void k_fill(const int* __restrict__ ei, const int* __restrict__ rowptr,
                                              int* __restrict__ cursor, int* __restrict__ colsrc) {
    int e = blockIdx.x * 256 + threadIdx.x;
    if (e < NE) {
        int d = ei[NE + e];
        int pos = rowptr[d] + atomicAdd(&cursor[d], 1);
        colsrc[pos] = ei[e];
    }
}

// ---------------- Degree sort (descending): counting sort into perm -------------

__global__ __launch_bounds__(256) void k_dhist(const int* __restrict__ rowptr,
                                               int* __restrict__ dcount) {
    __shared__ int lc[64];
    int t = threadIdx.x;
    if (t < 64) lc[t] = 0;
    __syncthreads();
    int n = blockIdx.x * 256 + t;
    if (n < NN) {
        int d = rowptr[n + 1] - rowptr[n];
        atomicAdd(&lc[min(d, 63)], 1);
    }
    __syncthreads();
    if (t < 64 && lc[t] > 0) atomicAdd(&dcount[t], lc[t]);
}

__global__ __launch_bounds__(64) void k_dscan(const int* __restrict__ dcount,
                                              int* __restrict__ doff) {
    int t = threadIdx.x;   // descending: bucket 63 first
    int s = 0;
    for (int b = t + 1; b < 64; ++b) s += dcount[b];
    doff[t] = s;
}

__global__ __launch_bounds__(256) void k_dfill(const int* __restrict__ rowptr,
                                               const int* __restrict__ doff,
                                               int* __restrict__ dcursor,
                                               int* __restrict__ perm) {
    __shared__ int lc[64], lbase[64];
    int t = threadIdx.x;
    if (t < 64) lc[t] = 0;
    __syncthreads();
    int n = blockIdx.x * 256 + t;
    int b = 0, my = 0;
    if (n < NN) {
        int d = rowptr[n + 1] - rowptr[n];
        b = min(d, 63);
        my = atomicAdd(&lc[b], 1);
    }
    __syncthreads();
    if (t < 64 && lc[t] > 0) lbase[t] = atomicAdd(&dcursor[t], lc[t]);
    __syncthreads();
    if (n < NN) perm[doff[b] + lbase[b] + my] = n;
}

// ---------------- Fused layer: gather -> LDS -> MFMA -> LDS -> full-line stores ----
// Gather identical to R12/R13 (coalesced 256-B row reads, 4-edge unroll, index
// prefetch). NEW: epilogue routes D through the wave-private Ab LDS slice so each
// global store writes one FULL 256-B contiguous row (16 lanes x 16 B per quad) --
// eliminates the 2-B scattered-store read-modify-write that was adding ~25 MB of
// L2-miss FETCH per dispatch. Values bitwise-identical to R13.

__global__ __launch_bounds__(256, 4) void k_gconv(
    const ushort_t* __restrict__ hin, const int* __restrict__ perm,
    const int* __restrict__ rowptr, const int* __restrict__ colsrc,
    const float* __restrict__ stats, const float* __restrict__ bng,
    const float* __restrict__ bnb,
    const ushort_t* __restrict__ Wt, const float* __restrict__ bias,
    ushort_t* __restrict__ hout, float* __restrict__ partials) {
    __shared__ ushort_t Ab[64 * ASTR];   // 17408 B
    __shared__ float sstat[256];
    int t = threadIdx.x;
    sstat[t] = 0.f;
    int wave = t >> 6, lane = t & 63;
    int l15 = lane & 15, quad = lane >> 4;
    int rowbase = blockIdx.x * 64 + wave * 16;

    // deferred BN affine for this lane's two features
    float sc0 = 1.f, sc1 = 1.f, sh0 = 0.f, sh1 = 0.f;
    {
        int c0 = lane * 2;
        if (stats != nullptr) {
            const float inv_n = 1.0f / (float)NN;
            float m0 = stats[c0] * inv_n, m1 = stats[c0 + 1] * inv_n;
            float var0 = fmaf(-m0, m0, stats[HD + c0] * inv_n);
            float var1 = fmaf(-m1, m1, stats[HD + c0 + 1] * inv_n);
            sc0 = bng[c0] * rsqrtf(var0 + 1e-5f);
            sc1 = bng[c0 + 1] * rsqrtf(var1 + 1e-5f);
            sh0 = bnb[c0] - m0 * sc0;
            sh1 = bnb[c0 + 1] - m1 * sc1;
        }
    }

    const ushort2* h2 = (const ushort2*)hin;
    #pragma unroll 1
    for (int g = 0; g < 4; ++g) {
        int b[4], d[4];
        #pragma unroll
        for (int i = 0; i < 4; ++i) {
            int idx = rowbase + g * 4 + i;
            bool v = idx < NN;
            int r = v ? perm[idx] : 0;
            b[i] = v ? rowptr[r] : 0;
            int e2 = v ? rowptr[r + 1] : 0;
            d[i] = e2 - b[i];
        }
        int maxd = max(max(d[0], d[1]), max(d[2], d[3]));
        float ax[4] = {0.f, 0.f, 0.f, 0.f};
        float ay[4] = {0.f, 0.f, 0.f, 0.f};

        int cs[16];
        #pragma unroll
        for (int eo = 0; eo < 4; ++eo)
            #pragma unroll
            for (int i = 0; i < 4; ++i)
                cs[eo * 4 + i] = colsrc[(eo < d[i]) ? b[i] + eo : 0];

        #pragma unroll 1
        for (int e = 0; e < maxd; e += 4) {
            ushort2 hv[16];
            #pragma unroll
            for (int u2 = 0; u2 < 16; ++u2)
                hv[u2] = h2[(size_t)cs[u2] * 64 + lane];
            int ncs[16];
            #pragma unroll
            for (int eo = 0; eo < 4; ++eo)
                #pragma unroll
                for (int i = 0; i < 4; ++i) {
                    int ee = e + 4 + eo;
                    ncs[eo * 4 + i] = colsrc[(ee < d[i]) ? b[i] + ee : 0];
                }
            #pragma unroll
            for (int eo = 0; eo < 4; ++eo)
                #pragma unroll
                for (int i = 0; i < 4; ++i) {
                    float m = (e + eo < d[i]) ? 1.f : 0.f;
                    ushort2 v = hv[eo * 4 + i];
                    ax[i] = fmaf(m, bf2f(v.x), ax[i]);
                    ay[i] = fmaf(m, bf2f(v.y), ay[i]);
                }
            #pragma unroll
            for (int u2 = 0; u2 < 16; ++u2) cs[u2] = ncs[u2];
        }

        #pragma unroll
        for (int i = 0; i < 4; ++i) {
            float degf = (float)d[i];
            float ox = fmaf(sc0, ax[i], degf * sh0);
            float oy = fmaf(sc1, ay[i], degf * sh1);
            int r = wave * 16 + g * 4 + i;
            *(ushort2*)&Ab[r * ASTR + 2 * lane] = make_ushort2(f2bf(ox), f2bf(oy));
        }
    }
    __syncthreads();   // LDS tile complete (also orders sstat zeroing)

    // A-fragments from LDS: A[m=l15][k=quad*8+j + s*32]
    short8 afrag[4];
    #pragma unroll
    for (int s = 0; s < 4; ++s)
        afrag[s] = *(const short8*)&Ab[(wave * 16 + l15) * ASTR + quad * 8 + s * 32];

    // MFMA phase (verified path)
    floatx4 acc[8];
    #pragma unroll
    for (int c = 0; c < 8; ++c) acc[c] = (floatx4){0.f, 0.f, 0.f, 0.f};
    #pragma unroll
    for (int c = 0; c < 8; ++c) {
        size_t boff = (size_t)(16 * c + l15) * 128 + quad * 8;
        #pragma unroll
        for (int s = 0; s < 4; ++s) {
            short8 bf = *(const short8*)(Wt + boff + 32 * s);
            acc[c] = __builtin_amdgcn_mfma_f32_16x16x32_bf16(afrag[s], bf, acc[c], 0, 0, 0);
        }
    }

    // Epilogue: bias+relu+round, stats, and write D back into own LDS slice.
    // (Wave-private slice; per-wave LDS ordering guarantees afrag reads precede.)
    int orow0 = rowbase + quad * 4;
    #pragma unroll
    for (int c = 0; c < 8; ++c) {
        int col = 16 * c + l15;
        float bv = bias[col];
        float ls = 0.f, lq = 0.f;
        #pragma unroll
        for (int i = 0; i < 4; ++i) {
            float v = fmaxf(acc[c][i] + bv, 0.f);
            ushort_t bb = f2bf(v);
            Ab[(wave * 16 + quad * 4 + i) * ASTR + col] = bb;
            if (orow0 + i < NN) {
                float vr = bf2f(bb);
                ls += vr;
                lq = fmaf(vr, vr, lq);
            }
        }
        ls += __shfl_xor(ls, 16, 64);
        ls += __shfl_xor(ls, 32, 64);
        lq += __shfl_xor(lq, 16, 64);
        lq += __shfl_xor(lq, 32, 64);
        if (quad == 0) {
            atomicAdd(&sstat[col], ls);
            atomicAdd(&sstat[128 + col], lq);
        }
    }

    // Full-line stores: per iteration, each quad stores one FULL 256-B row
    // (16 lanes x contiguous 16 B). No sub-line RMW at L2.
    #pragma unroll
    for (int it = 0; it < 4; ++it) {
        int ridx = rowbase + it * 4 + quad;
        if (ridx < NN) {
            int pr = perm[ridx];
            short8 v = *(const short8*)&Ab[(wave * 16 + it * 4 + quad) * ASTR + l15 * 8];
            *(short8*)(hout + (size_t)pr * 128 + l15 * 8) = v;
        }
    }

    __syncthreads();
    partials[(size_t)blockIdx.x * 256 + t] = sstat[t];
}

// ---------------- Partial-stats reduction: 1563 x 256 -> 256 (64 blocks) -----------

__global__ __launch_bounds__(256) void k_red(const float* __restrict__ partials,
                                             float* __restrict__ stats) {
    int t = threadIdx.x;
    float s = 0.f;
    for (int r = blockIdx.x; r < NB; r += 64) s += partials[(size_t)r * 256 + t];
    atomicAdd(&stats[t], s);
}

// ---------------- Pooling, phase 1: per-(graph,slice) partial sums (bf16 h) ---------

__device__ __forceinline__ int lowerb(const int* __restrict__ b, int n, int key) {
    int lo = 0, hi = n;
    while (lo < hi) {
        int mid = (lo + hi) >> 1;
        if (b[mid] < key) lo = mid + 1;
        else hi = mid;
    }
    return lo;
}

__global__ __launch_bounds__(256) void k_pool1(
    const ushort_t* __restrict__ h, const int* __restrict__ batch,
    float* __restrict__ ppart) {
    int g = blockIdx.x >> 4;
    int sl = blockIdx.x & (PSL - 1);
    int lo = lowerb(batch, NN, g);
    int hi = lowerb(batch, NN, g + 1);
    int cnt = hi - lo;
    int a = lo + (int)(((long long)cnt * sl) >> 4);
    int b = lo + (int)(((long long)cnt * (sl + 1)) >> 4);
    int wave = threadIdx.x >> 6, lane = threadIdx.x & 63;
    const ushort2* h2 = (const ushort2*)h;
    float ax = 0.f, ay = 0.f;
    for (int n = a + wave; n < b; n += 4) {
        ushort2 v = h2[(size_t)n * 64 + lane];
        ax += bf2f(v.x);
        ay += bf2f(v.y);
    }
    __shared__ float2 red[4][64];
    red[wave][lane] = make_float2(ax, ay);
    __syncthreads();
    if (wave == 0) {
        float sx = 0.f, sy = 0.f;
        for (int w = 0; w < 4; ++w) {
            sx += red[w][lane].x;
            sy += red[w][lane].y;
        }
        ((float2*)ppart)[(size_t)blockIdx.x * 64 + lane] = make_float2(sx, sy);
    }
}

// ---------------- Pooling, phase 2: combine slices + deferred BN affine ----------------

__global__ __launch_bounds__(64) void k_pool2(
    const float* __restrict__ ppart, const int* __restrict__ batch,
    const float* __restrict__ stats, const float* __restrict__ bng, const float* __restrict__ bnb,
    float* __restrict__ pooled) {
    int g = blockIdx.x;
    int lane = threadIdx.x;
    float sx = 0.f, sy = 0.f;
    #pragma unroll
    for (int s = 0; s < PSL; ++s) {
        float2 v = ((const float2*)ppart)[(size_t)(g * PSL + s) * 64 + lane];
        sx += v.x;
        sy += v.y;
    }
    int cnt = lowerb(batch, NN, g + 1) - lowerb(batch, NN, g);
    int c0 = lane * 2;
    const float inv_n = 1.0f / (float)NN;
    float m0 = stats[c0] * inv_n, m1 = stats[c0 + 1] * inv_n;
    float var0 = fmaf(-m0, m0, stats[HD + c0] * inv_n);
    float var1 = fmaf(-m1, m1, stats[HD + c0 + 1] * inv_n);
    float sc0 = bng[c0] * rsqrtf(var0 + 1e-5f);
    float sc1 = bng[c0 + 1] * rsqrtf(var1 + 1e-5f);
    float sh0 = bnb[c0] - m0 * sc0;
    float sh1 = bnb[c0 + 1] - m1 * sc1;
    float denom = fmaxf((float)cnt, 1.f);
    float2 o;
    o.x = (sc0 * sx + (float)cnt * sh0) / denom;
    o.y = (sc1 * sy + (float)cnt * sh1) / denom;
    ((float2*)pooled)[g * 64 + lane] = o;
}

// ---------------- MLP head + log_softmax (one wave per graph) ----------------

__global__ __launch_bounds__(64) void k_head(
    const float* __restrict__ pooled, const float* __restrict__ w1, const float* __restrict__ b1,
    const float* __restrict__ w2, const float* __restrict__ b2, float* __restrict__ out) {
    int g = blockIdx.x;
    int j = threadIdx.x;
    float hid = b1[j];
    const float* p = pooled + g * 128;
    #pragma unroll 8
    for (int k = 0; k < 128; ++k) hid = fmaf(p[k], w1[k * 64 + j], hid);
    float o[4];
    #pragma unroll
    for (int c = 0; c < 4; ++c) {
        float v = hid * w2[j * 4 + c];
        #pragma unroll
        for (int off = 1; off < 64; off <<= 1) v += __shfl_xor(v, off, 64);
        o[c] = v + b2[c];
    }
    if (j == 0) {
        float mx = fmaxf(fmaxf(o[0], o[1]), fmaxf(o[2], o[3]));
        float se = expf(o[0] - mx) + expf(o[1] - mx) + expf(o[2] - mx) + expf(o[3] - mx);
        float ls = mx + logf(se);
        #pragma unroll
        for (int c = 0; c < 4; ++c) out[g * 4 + c] = o[c] - ls;
    }
}

extern "C" void kernel_launch(void* const* d_in, const int* in_sizes, int n_in,
                              void* d_out, int out_size, void* d_ws, size_t ws_size,
                              hipStream_t stream) {
    const float* x = (const float*)d_in[0];
    const int* ei = (const int*)d_in[1];
    const int* batch = (const int*)d_in[2];
    const float* conv_w = (const float*)d_in[3];
    const float* conv_b = (const float*)d_in[4];
    const float* bn_g = (const float*)d_in[5];
    const float* bn_b = (const float*)d_in[6];
    const float* l1w = (const float*)d_in[7];
    const float* l1b = (const float*)d_in[8];
    const float* l2w = (const float*)d_in[9];
    const float* l2b = (const float*)d_in[10];
    float* out = (float*)d_out;
    (void)in_sizes; (void)n_in; (void)out_size; (void)ws_size;

    char* ws = (char*)d_ws;
    int* counts = (int*)(ws + 0);               // 400000 B
    int* dcount = (int*)(ws + 0);               // 256 B   (after k_fill)
    int* dcursor = (int*)(ws + 256);            // 256 B
    int* doff = (int*)(ws + 512);               // 256 B
    int* cursor = (int*)(ws + 400000);          // 400000 B
    int* perm = (int*)(ws + 400000);            // reuse   (after k_fill)
    float* stats = (float*)(ws + 800000);       // 6*256 floats = 6144 B
    const size_t zero_bytes = 806144;           // counts + cursor + stats
    int* rowptr = (int*)(ws + 806144);          // 100001 ints
    int* bsums = (int*)(ws + 1206400);          // 391 ints
    int* colsrc = (int*)(ws + 1208192);         // 600000 ints -> ends 3608192
    float* pooled = (float*)(ws + 3608192);     // 64*128 floats -> ends 3640960
    float* ppart = (float*)(ws + 3641344);      // 1024*128 floats -> ends 4165632
    float* partials = (float*)(ws + 4165632);   // 1563*256 floats -> ends 5766144
    ushort_t* xb = (ushort_t*)(ws + 5766656);   // 25600000 B -> ends 31366656
    ushort_t* hb0 = (ushort_t*)(ws + 31366656); // 25600000 B -> ends 56966656
    ushort_t* hb1 = (ushort_t*)(ws + 56966656); // 25600000 B -> ends 82566656
    ushort_t* wtbuf = (ushort_t*)(ws + 82566656); // 196608 B -> ends 82763264

    hipMemsetAsync(ws, 0, zero_bytes, stream);

    k_cast<<<(NN * 32 + 255) / 256, 256, 0, stream>>>(x, xb);
    k_wcast<<<NL, 256, 0, stream>>>(conv_w, wtbuf);

    int ebl = (NE + 255) / 256;
    int nb1 = (NN + 255) / 256;  // 391
    k_hist<<<ebl, 256, 0, stream>>>(ei, counts);
    k_scan1<<<nb1, 256, 0, stream>>>(counts, bsums);
    k_scan2<<<1, 512, 0, stream>>>(bsums, nb1);
    k_scan3<<<nb1, 256, 0, stream>>>(counts, bsums, rowptr);
    k_fill<<<ebl, 256, 0, stream>>>(ei, rowptr, cursor, colsrc);

    // degree counting sort (descending) into perm
    hipMemsetAsync(ws, 0, 512, stream);   // dcount + dcursor
    k_dhist<<<nb1, 256, 0, stream>>>(rowptr, dcount);
    k_dscan<<<1, 64, 0, stream>>>(dcount, doff);
    k_dfill<<<nb1, 256, 0, stream>>>(rowptr, doff, dcursor, perm);

    // ping-pong h buffers: gconv reads hin, writes hout (never in place)
    ushort_t* hb[2] = {hb0, hb1};
    for (int L = 0; L < NL; ++L) {
        const ushort_t* hin = (L == 0) ? xb : hb[(L + 1) & 1];
        ushort_t* hout = hb[L & 1];
        const float* lstats = (L == 0) ? nullptr : (stats + (L - 1) * 256);
        const float* lg = (L == 0) ? nullptr : (bn_g + (L - 1) * 128);
        const float* lb = (L == 0) ? nullptr : (bn_b + (L - 1) * 128);
        k_gconv<<<NB, 256, 0, stream>>>(hin, perm, rowptr, colsrc, lstats, lg, lb,
                                        wtbuf + L * 16384, conv_b + L * 128,
                                        hout, partials);
        k_red<<<64, 256, 0, stream>>>(partials, stats + L * 256);
    }
    // final h is hb[5&1] = hb1
    k_pool1<<<NG * PSL, 256, 0, stream>>>(hb1, batch, ppart);
    k_pool2<<<NG, 64, 0, stream>>>(ppart, batch, stats + 5 * 256, bn_g + 5 * 128, bn_b + 5 * 128, pooled);
    k_head<<<NG, 64, 0, stream>>>(pooled, l1w, l1b, l2w, l2b, out);
}